// Round 3
// baseline (391.966 us; speedup 1.0000x reference)
//
#include <hip/hip_runtime.h>
#include <hip/hip_bf16.h>

#define NN 50000
#define EE 800000
#define ETOT 850000   // EE + NN self-loops
#define FIN 500
#define HC 128        // 8 heads * 16 ch
#define NH 8
#define CH 16
#define NC 7

// canonical fp32 weight-buffer offsets
#define OW1  0
#define OAS1 64000
#define OAD1 64128
#define OB1  64256
#define OW2  64384
#define OAS2 65280
#define OAD2 65287
#define OB2  65294
#define WTOT 65301

// MFMA gemm1: 16 rows per 1-wave block, LDS-free K-loop
#define GK   32
#define KPAD 512
#define ESTR 133   // epilogue LDS stride (5 mod 32 -> conflict-light)

typedef __hip_bfloat16 bf16;
typedef __attribute__((ext_vector_type(8))) short short8;
typedef __attribute__((ext_vector_type(4))) float f32x4;

__device__ __forceinline__ float b2f(const bf16 v) { return __bfloat162float(v); }
__device__ __forceinline__ float lrelu(float v) { return fmaxf(v, 0.2f * v); }
__device__ __forceinline__ float elog(float v) { return __expf(fminf(lrelu(v), 30.f)); }
__device__ __forceinline__ float blo(unsigned w) { return __uint_as_float(w << 16); }
__device__ __forceinline__ float bhi(unsigned w) { return __uint_as_float(w & 0xffff0000u); }
__device__ __forceinline__ unsigned short f2bu(float f)
{
    bf16 h = __float2bfloat16(f);
    return *(unsigned short*)&h;
}
__device__ __forceinline__ unsigned pk2(float a, float b)
{
    return (unsigned)f2bu(a) | ((unsigned)f2bu(b) << 16);
}

// low-word read: int64 indices are < 2^31, little-endian -> low dword suffices
__device__ __forceinline__ int eread(const void* __restrict__ eidx, long long i, int is64)
{
    if (is64) return ((const int*)eidx)[2 * i];
    return ((const int*)eidx)[i];
}

// ---------------- dtype detection + rowptr sentinel ----------------
__global__ void detect_kernel(const unsigned short* __restrict__ xraw,
                              const unsigned int* __restrict__ eraw,
                              int* __restrict__ flags, int* __restrict__ rowptr)
{
    __shared__ int s_insane, s_oddnz;
    if (threadIdx.x == 0) { s_insane = 0; s_oddnz = 0; }
    __syncthreads();
    int insane = 0;
    for (int i = threadIdx.x; i < 8192; i += 256) {
        const unsigned int bits = ((unsigned int)xraw[i]) << 16;
        const float v = __uint_as_float(bits);
        const float a = fabsf(v);
        const bool sane = (v == 0.0f) || (a >= 1e-30f && a <= 1e4f);
        if (!sane) insane++;
    }
    int oddnz = 0;
    for (int i = threadIdx.x; i < 512; i += 256) {
        if (eraw[2 * i + 1] != 0u) oddnz++;
    }
    atomicAdd(&s_insane, insane);
    atomicAdd(&s_oddnz, oddnz);
    __syncthreads();
    if (threadIdx.x == 0) {
        flags[0] = (s_insane < 256) ? 1 : 0;
        flags[1] = (s_oddnz == 0) ? 1 : 0;
        rowptr[NN] = ETOT;   // sentinel: rowptr holds immutable starts + end
    }
}

// ---------------- canonicalize weights to fp32 + build w1t (merged) ----------------
__global__ void conv_all_kernel(const void* W1, const void* as1, const void* ad1, const void* b1,
                                const void* W2, const void* as2, const void* ad2, const void* b2,
                                float* __restrict__ wc, unsigned short* __restrict__ w1t,
                                const int* __restrict__ flags)
{
    const int i = blockIdx.x * blockDim.x + threadIdx.x;
    const int isbf = flags[0];
    if (i < WTOT) {
        const void* src; int off;
        if (i < OAS1)      { src = W1;  off = i - OW1; }
        else if (i < OAD1) { src = as1; off = i - OAS1; }
        else if (i < OB1)  { src = ad1; off = i - OAD1; }
        else if (i < OW2)  { src = b1;  off = i - OB1; }
        else if (i < OAS2) { src = W2;  off = i - OW2; }
        else if (i < OAD2) { src = as2; off = i - OAD2; }
        else if (i < OB2)  { src = ad2; off = i - OAD2 + 0; }
        else               { src = b2;  off = i - OB2; }
        // fix the two small ranges explicitly (avoid accidental typo above)
        if (i >= OAD2 && i < OB2) { src = ad2; off = i - OAD2; }
        float v;
        if (isbf) v = b2f(((const bf16*)src)[off]);
        else      v = ((const float*)src)[off];
        wc[i] = v;
    }
    if (i < HC * KPAD) {
        const int col = i >> 9;
        const int k   = i & (KPAD - 1);
        float v = 0.f;
        if (k < FIN) {
            if (isbf) v = b2f(((const bf16*)W1)[k * HC + col]);
            else      v = ((const float*)W1)[k * HC + col];
        }
        w1t[i] = f2bu(v);
    }
}

// ---------------- CSR build: histogram of dst ----------------
__global__ void hist_kernel(const void* __restrict__ eidx, int* __restrict__ deg,
                            const int* __restrict__ flags)
{
    const int e = blockIdx.x * blockDim.x + threadIdx.x;
    if (e >= ETOT) return;
    int d;
    if (e < EE) d = eread(eidx, (long long)EE + e, flags[1]);
    else        d = e - EE;
    if ((unsigned)d < (unsigned)NN) atomicAdd(&deg[d], 1);
}

// ---------------- scan k1 ----------------
__global__ void scan_k1_kernel(const int* __restrict__ deg, int* __restrict__ bsum)
{
    __shared__ int lds[256];
    const int i = blockIdx.x * 256 + threadIdx.x;
    lds[threadIdx.x] = (i < NN) ? deg[i] : 0;
    __syncthreads();
    for (int s = 128; s > 0; s >>= 1) {
        if (threadIdx.x < s) lds[threadIdx.x] += lds[threadIdx.x + s];
        __syncthreads();
    }
    if (threadIdx.x == 0) bsum[blockIdx.x] = lds[0];
}

// ---------------- scan k2 ----------------
__global__ void scan_k2_kernel(int* __restrict__ bsum)
{
    __shared__ int a[256], b[256], orig[256];
    const int t = threadIdx.x;
    a[t] = bsum[t]; orig[t] = a[t];
    __syncthreads();
    int* cur = a; int* nxt = b;
    for (int off = 1; off < 256; off <<= 1) {
        nxt[t] = cur[t] + ((t >= off) ? cur[t - off] : 0);
        __syncthreads();
        int* tmp = cur; cur = nxt; nxt = tmp;
    }
    bsum[t] = cur[t] - orig[t];
}

// ---------------- scan k3: rowptr[i] = exclusive start of node i ----------------
__global__ void scan_k3_kernel(const int* __restrict__ deg, const int* __restrict__ bsum,
                               int* __restrict__ rowptr)
{
    __shared__ int a[256], b[256], own[256];
    const int t = threadIdx.x;
    const int i = blockIdx.x * 256 + t;
    const int v = (i < NN) ? deg[i] : 0;
    a[t] = v; own[t] = v;
    __syncthreads();
    int* cur = a; int* nxt = b;
    for (int off = 1; off < 256; off <<= 1) {
        nxt[t] = cur[t] + ((t >= off) ? cur[t - off] : 0);
        __syncthreads();
        int* tmp = cur; cur = nxt; nxt = tmp;
    }
    if (i < NN) rowptr[i] = bsum[blockIdx.x] + cur[t] - own[t];
}

// ---------------- CSR scatter: pos = rowptr[d] + atomic cursor ----------------
__global__ void scatter_kernel(const void* __restrict__ eidx, const int* __restrict__ rowptr,
                               int* __restrict__ cur, int* __restrict__ esrc_sorted,
                               const int* __restrict__ flags)
{
    const int e = blockIdx.x * blockDim.x + threadIdx.x;
    if (e >= ETOT) return;
    int s, d;
    if (e < EE) {
        s = eread(eidx, e, flags[1]);
        d = eread(eidx, (long long)EE + e, flags[1]);
    } else s = d = e - EE;
    if ((unsigned)s >= (unsigned)NN || (unsigned)d >= (unsigned)NN) return;
    const int pos = rowptr[d] + atomicAdd(&cur[d], 1);
    if ((unsigned)pos < (unsigned)ETOT) esrc_sorted[pos] = s;
}

// ---------------- GEMM1 v3: LDS-free, barrier-free MFMA K-loop ----------------
// One wave per block owns 16 rows x 128 cols. A and B fragments are loaded
// DIRECTLY from global into MFMA operand registers (fragment layout == memory
// layout), ping-pong double buffered. w1t (128 KB) is L2-resident. LDS is used
// only in the per-wave epilogue to reshape acc -> vectorized h1 + att1 dots.
__global__ __launch_bounds__(64, 3) void gemm1_mfma_kernel(
    const void* __restrict__ x, const unsigned short* __restrict__ w1t,
    bf16* __restrict__ h1, const float* __restrict__ wc,
    float* __restrict__ a_src1, float* __restrict__ a_dst1,
    const int* __restrict__ flags)
{
    __shared__ float Esl[16][ESTR];   // 16 rows x 133 f32 = 8.5 KB
    __shared__ float attw[256];       // as1[128] | ad1[128]

    const int t    = threadIdx.x;     // 0..63
    const int m15  = t & 15;
    const int quad = t >> 4;
    const int r0   = blockIdx.x * 16; // 3125*16 = 50000 exactly: no row guards
    const int isbf = flags[0];
    const float* xf = (const float*)x;
    const unsigned short* xb = (const unsigned short*)x;

    attw[t]       = wc[OAS1 + t];          // as[0..63]
    attw[t + 64]  = wc[OAS1 + 64 + t];     // as[64..127]
    attw[t + 128] = wc[OAD1 + t];
    attw[t + 192] = wc[OAD1 + 64 + t];

    const size_t abase = (size_t)(r0 + m15) * FIN;   // A row for this lane
    const unsigned short* bbase = w1t + (size_t)m15 * KPAD + quad * 8;

    f32x4 acc[8];
#pragma unroll
    for (int j = 0; j < 8; ++j) acc[j] = (f32x4){0.f, 0.f, 0.f, 0.f};

    // A fragment loader: 8 contiguous bf16 at row (r0+m15), k = kt*32 + quad*8.
    // kt==15 tail: k>=500 must be zero (w1t is zero-padded so garbage*0 would be
    // fine numerically, but we must not read past the end of x).
    auto loadA = [&](int kt) -> short8 {
        uint4 r = make_uint4(0u, 0u, 0u, 0u);
        const int k0 = kt * GK + quad * 8;
        if (kt < 15 || quad < 2) {
            if (isbf) {
                // 8B-aligned always (row stride 1000 B); avoid 16B-misalign risk
                const uint2 lo = *(const uint2*)(xb + abase + k0);
                const uint2 hi = *(const uint2*)(xb + abase + k0 + 4);
                r.x = lo.x; r.y = lo.y; r.z = hi.x; r.w = hi.y;
            } else {
                const float4 v0 = *(const float4*)(xf + abase + k0);
                const float4 v1 = *(const float4*)(xf + abase + k0 + 4);
                r.x = pk2(v0.x, v0.y); r.y = pk2(v0.z, v0.w);
                r.z = pk2(v1.x, v1.y); r.w = pk2(v1.z, v1.w);
            }
        } else if (quad == 2) {          // k 496..499 valid, 500..503 zero
            if (isbf) {
                const uint2 lo = *(const uint2*)(xb + abase + k0);
                r.x = lo.x; r.y = lo.y;
            } else {
                const float4 v0 = *(const float4*)(xf + abase + k0);
                r.x = pk2(v0.x, v0.y); r.y = pk2(v0.z, v0.w);
            }
        }                                 // quad==3: all zero
        return *(short8*)&r;
    };
    auto loadB = [&](int kt, short8* b) {
        const unsigned short* gp = bbase + kt * GK;
#pragma unroll
        for (int ct = 0; ct < 8; ++ct)
            b[ct] = *(const short8*)(gp + (size_t)ct * 16 * KPAD);
    };

    short8 a0, a1, b0[8], b1[8];
    a0 = loadA(0);
    loadB(0, b0);
#pragma unroll
    for (int k2 = 0; k2 < 8; ++k2) {
        a1 = loadA(2 * k2 + 1);
        loadB(2 * k2 + 1, b1);
#pragma unroll
        for (int ct = 0; ct < 8; ++ct)
            acc[ct] = __builtin_amdgcn_mfma_f32_16x16x32_bf16(a0, b0[ct], acc[ct], 0, 0, 0);
        if (k2 < 7) {
            a0 = loadA(2 * k2 + 2);
            loadB(2 * k2 + 2, b0);
        }
#pragma unroll
        for (int ct = 0; ct < 8; ++ct)
            acc[ct] = __builtin_amdgcn_mfma_f32_16x16x32_bf16(a1, b1[ct], acc[ct], 0, 0, 0);
    }

    // ---- epilogue: acc -> LDS tile, then vectorized h1 + att1 ----
#pragma unroll
    for (int ct = 0; ct < 8; ++ct)
#pragma unroll
        for (int reg = 0; reg < 4; ++reg)
            Esl[quad * 4 + reg][ct * 16 + m15] = acc[ct][reg];
    __syncthreads();

    {
        // h1: thread t -> row t&15, cols (t>>4)*32 .. +32
        const int row = t & 15;
        const int c0  = (t >> 4) * 32;
        const int gr  = r0 + row;
        const float* ep = &Esl[row][c0];
        uint4 w0, w1;
        w0.x = pk2(ep[0],  ep[1]);  w0.y = pk2(ep[2],  ep[3]);
        w0.z = pk2(ep[4],  ep[5]);  w0.w = pk2(ep[6],  ep[7]);
        w1.x = pk2(ep[8],  ep[9]);  w1.y = pk2(ep[10], ep[11]);
        w1.z = pk2(ep[12], ep[13]); w1.w = pk2(ep[14], ep[15]);
        *(uint4*)(h1 + (size_t)gr * HC + c0)     = w0;
        *(uint4*)(h1 + (size_t)gr * HC + c0 + 8) = w1;
        uint4 w2, w3;
        w2.x = pk2(ep[16], ep[17]); w2.y = pk2(ep[18], ep[19]);
        w2.z = pk2(ep[20], ep[21]); w2.w = pk2(ep[22], ep[23]);
        w3.x = pk2(ep[24], ep[25]); w3.y = pk2(ep[26], ep[27]);
        w3.z = pk2(ep[28], ep[29]); w3.w = pk2(ep[30], ep[31]);
        *(uint4*)(h1 + (size_t)gr * HC + c0 + 16) = w2;
        *(uint4*)(h1 + (size_t)gr * HC + c0 + 24) = w3;

        // att1: thread t -> (row t&15, heads t>>4 and (t>>4)+4)
#pragma unroll
        for (int hp2 = 0; hp2 < 2; ++hp2) {
            const int hh = (t >> 4) + hp2 * 4;
            const float* rp = &Esl[row][hh * 16];
            const float* as = &attw[hh * 16];
            const float* ad = &attw[128 + hh * 16];
            float s = 0.f, d = 0.f;
#pragma unroll
            for (int u = 0; u < 16; ++u) {
                s += rp[u] * as[u];
                d += rp[u] * ad[u];
            }
            a_src1[(size_t)gr * NH + hh] = s;
            a_dst1[(size_t)gr * NH + hh] = d;
        }
    }
}

// ---------------- layer-1 fused gather + fused GEMM2/bias/relu + fused att2 ----------------
__global__ __launch_bounds__(256) void gather1_kernel(
    const int* __restrict__ rowptr, const int* __restrict__ esrc_sorted,
    const float* __restrict__ a_src, const float* __restrict__ a_dst,
    const bf16* __restrict__ h1, const float* __restrict__ wc,
    float* __restrict__ h2, float* __restrict__ a_src2, float* __restrict__ a_dst2)
{
    __shared__ float W2s[HC * NC];
    __shared__ float B1s[HC];
    for (int i = threadIdx.x; i < HC * NC; i += 256) W2s[i] = wc[OW2 + i];
    if (threadIdx.x < HC) B1s[threadIdx.x] = wc[OB1 + threadIdx.x];
    __syncthreads();

    const int node = blockIdx.x * 4 + (threadIdx.x >> 6);
    if (node >= NN) return;
    const int lane = threadIdx.x & 63;
    const int h = lane >> 3;
    const float ad = a_dst[node * NH + h];
    const int start = rowptr[node];
    const int end   = rowptr[node + 1];
    float acc0 = 0.f, acc1 = 0.f, den = 0.f;
    int i = start;
    for (; i + 8 <= end; i += 8) {
        int   sv[8];
        float ev[8];
        unsigned wv[8];
#pragma unroll
        for (int j = 0; j < 8; ++j) sv[j] = esrc_sorted[i + j];
#pragma unroll
        for (int j = 0; j < 8; ++j) ev[j] = a_src[sv[j] * NH + h];
#pragma unroll
        for (int j = 0; j < 8; ++j) wv[j] = *(const unsigned*)(h1 + (size_t)sv[j] * HC + 2 * lane);
#pragma unroll
        for (int j = 0; j < 8; ++j) {
            const float n = elog(ev[j] + ad);
            acc0 += n * blo(wv[j]);
            acc1 += n * bhi(wv[j]);
            den  += n;
        }
    }
    for (; i < end; ++i) {
        const int s = esrc_sorted[i];
        const float num = elog(a_src[s * NH + h] + ad);
        const unsigned w = *(const unsigned*)(h1 + (size_t)s * HC + 2 * lane);
        acc0 += num * blo(w);
        acc1 += num * bhi(w);
        den  += num;
    }
    const float inv = 1.f / (den + 1e-16f);

    // fused GEMM2: this wave holds the whole out1 row (2 channels / lane).
    const int k0 = 2 * lane;
    const float r0v = fmaxf(acc0 * inv + B1s[k0],     0.f);
    const float r1v = fmaxf(acc1 * inv + B1s[k0 + 1], 0.f);
    float p[NC];
#pragma unroll
    for (int c = 0; c < NC; ++c)
        p[c] = r0v * W2s[k0 * NC + c] + r1v * W2s[(k0 + 1) * NC + c];
    // 64-lane butterfly reduce (7 channels)
#pragma unroll
    for (int m = 1; m < 64; m <<= 1) {
#pragma unroll
        for (int c = 0; c < NC; ++c) p[c] += __shfl_xor(p[c], m);
    }
    if (lane == 0) {
        float ps = 0.f, pd = 0.f;
        float* hp = h2 + (size_t)node * NC;
#pragma unroll
        for (int c = 0; c < NC; ++c) {
            hp[c] = p[c];
            ps += p[c] * wc[OAS2 + c];
            pd += p[c] * wc[OAD2 + c];
        }
        a_src2[node] = ps;
        a_dst2[node] = pd;
    }
}

// ---------------- layer-2 fused gather ----------------
__global__ void gather2_kernel(
    const int* __restrict__ rowptr, const int* __restrict__ esrc_sorted,
    const float* __restrict__ a_src, const float* __restrict__ a_dst,
    const float* __restrict__ h2, const float* __restrict__ wc,
    void* __restrict__ out, const int* __restrict__ flags)
{
    const int node = blockIdx.x * 32 + (threadIdx.x >> 3);
    if (node >= NN) return;
    const int c = threadIdx.x & 7;
    const float ad = a_dst[node];
    const int start = rowptr[node];
    const int end   = rowptr[node + 1];
    const int cc = (c < NC) ? c : 0;
    float acc = 0.f, den = 0.f;
    int i = start;
    for (; i + 4 <= end; i += 4) {
        const int s0 = esrc_sorted[i + 0];
        const int s1 = esrc_sorted[i + 1];
        const int s2 = esrc_sorted[i + 2];
        const int s3 = esrc_sorted[i + 3];
        const float e0 = a_src[s0];
        const float e1 = a_src[s1];
        const float e2 = a_src[s2];
        const float e3 = a_src[s3];
        const float v0 = h2[s0 * NC + cc];
        const float v1 = h2[s1 * NC + cc];
        const float v2 = h2[s2 * NC + cc];
        const float v3 = h2[s3 * NC + cc];
        const float n0 = elog(e0 + ad);
        const float n1 = elog(e1 + ad);
        const float n2 = elog(e2 + ad);
        const float n3 = elog(e3 + ad);
        acc += n0 * v0 + n1 * v1 + n2 * v2 + n3 * v3;
        den += n0 + n1 + n2 + n3;
    }
    for (; i < end; ++i) {
        const int s = esrc_sorted[i];
        const float num = elog(a_src[s] + ad);
        den += num;
        acc += num * h2[s * NC + cc];
    }
    if (c >= NC) return;
    const float v = acc / (den + 1e-16f) + wc[OB2 + c];
    if (flags[0]) ((bf16*)out)[node * NC + c] = __float2bfloat16(v);
    else          ((float*)out)[node * NC + c] = v;
}

extern "C" void kernel_launch(void* const* d_in, const int* in_sizes, int n_in,
                              void* d_out, int out_size, void* d_ws, size_t ws_size,
                              hipStream_t stream)
{
    const void* x        = d_in[0];
    const void* eidx     = d_in[1];
    const void* W1       = d_in[2];
    const void* att_src1 = d_in[3];
    const void* att_dst1 = d_in[4];
    const void* b1       = d_in[5];
    const void* W2       = d_in[6];
    const void* att_src2 = d_in[7];
    const void* att_dst2 = d_in[8];
    const void* b2       = d_in[9];

    float* ws = (float*)d_ws;
    size_t o = 0;
    int*   flags  = (int*)(ws + o);            o += 16;
    float* wc     = ws + o;                    o += 65312;
    unsigned short* w1t = (unsigned short*)(ws + o); o += (HC * KPAD) / 2;
    int*   deg    = (int*)(ws + o);            o += 50000;
    int*   cur    = (int*)(ws + o);            o += 50000;   // contiguous with deg for one memset
    int*   rowptr = (int*)(ws + o);            o += 50016;
    int*   bsum   = (int*)(ws + o);            o += 256;
    int*   esrt   = (int*)(ws + o);            o += 850000;
    bf16*  h1     = (bf16*)(ws + o);           o += (size_t)NN * HC / 2;
    float* a_src1 = ws + o;                    o += (size_t)NN * NH;
    float* a_dst1 = ws + o;                    o += (size_t)NN * NH;
    float* h2     = ws + o;                    o += (size_t)NN * NC;
    float* a_src2 = ws + o;                    o += NN;
    float* a_dst2 = ws + o;                    o += NN;

    detect_kernel<<<1, 256, 0, stream>>>((const unsigned short*)x, (const unsigned int*)eidx,
                                         flags, rowptr);
    conv_all_kernel<<<(HC * KPAD + 255) / 256, 256, 0, stream>>>(
        W1, att_src1, att_dst1, b1, W2, att_src2, att_dst2, b2, wc, w1t, flags);
    hipMemsetAsync(deg, 0, 2 * (size_t)NN * sizeof(int), stream);
    hist_kernel<<<(ETOT + 255) / 256, 256, 0, stream>>>(eidx, deg, flags);
    scan_k1_kernel<<<(NN + 255) / 256, 256, 0, stream>>>(deg, bsum);
    scan_k2_kernel<<<1, 256, 0, stream>>>(bsum);
    scan_k3_kernel<<<(NN + 255) / 256, 256, 0, stream>>>(deg, bsum, rowptr);
    scatter_kernel<<<(ETOT + 255) / 256, 256, 0, stream>>>(eidx, rowptr, cur, esrt, flags);

    gemm1_mfma_kernel<<<NN / 16, 64, 0, stream>>>(x, w1t, h1, wc, a_src1, a_dst1, flags);
    gather1_kernel<<<(NN + 3) / 4, 256, 0, stream>>>(rowptr, esrt, a_src1, a_dst1, h1, wc,
                                                     h2, a_src2, a_dst2);
    gather2_kernel<<<(NN + 31) / 32, 256, 0, stream>>>(rowptr, esrt, a_src2, a_dst2, h2, wc,
                                                       d_out, flags);
}

// Round 4
// 368.124 us; speedup vs baseline: 1.0648x; 1.0648x over previous
//
#include <hip/hip_runtime.h>
#include <hip/hip_bf16.h>

#define NN 50000
#define EE 800000
#define ETOT 850000   // EE + NN self-loops
#define FIN 500
#define HC 128        // 8 heads * 16 ch
#define NH 8
#define CH 16
#define NC 7

// canonical fp32 weight-buffer offsets
#define OW1  0
#define OAS1 64000
#define OAD1 64128
#define OB1  64256
#define OW2  64384
#define OAS2 65280
#define OAD2 65287
#define OB2  65294
#define WTOT 65301

// MFMA gemm1 tiling: 64 rows x 128 cols per block, BK=64, 8 waves
#define BM   64
#define BKK  64
#define NKT  8
#define KPAD 512

typedef __hip_bfloat16 bf16;
typedef __attribute__((ext_vector_type(8))) short short8;
typedef __attribute__((ext_vector_type(4))) float f32x4;

__device__ __forceinline__ float b2f(const bf16 v) { return __bfloat162float(v); }
__device__ __forceinline__ float lrelu(float v) { return fmaxf(v, 0.2f * v); }
__device__ __forceinline__ float elog(float v) { return __expf(fminf(lrelu(v), 30.f)); }
__device__ __forceinline__ float blo(unsigned w) { return __uint_as_float(w << 16); }
__device__ __forceinline__ float bhi(unsigned w) { return __uint_as_float(w & 0xffff0000u); }
__device__ __forceinline__ unsigned short f2bu(float f)
{
    bf16 h = __float2bfloat16(f);
    return *(unsigned short*)&h;
}
__device__ __forceinline__ unsigned pk2(float a, float b)
{
    return (unsigned)f2bu(a) | ((unsigned)f2bu(b) << 16);
}

// async global->LDS, 16B per lane; lds dest is wave-uniform base + lane*16
__device__ __forceinline__ void gload16(const unsigned short* g, unsigned short* l)
{
    __builtin_amdgcn_global_load_lds(
        (const __attribute__((address_space(1))) unsigned int*)(const void*)g,
        (__attribute__((address_space(3))) unsigned int*)(void*)l,
        16, 0, 0);
}

// low-word read: int64 indices are < 2^31, little-endian -> low dword suffices
__device__ __forceinline__ int eread(const void* __restrict__ eidx, long long i, int is64)
{
    if (is64) return ((const int*)eidx)[2 * i];
    return ((const int*)eidx)[i];
}

// ---------------- dtype detection + rowptr sentinel ----------------
__global__ void detect_kernel(const unsigned short* __restrict__ xraw,
                              const unsigned int* __restrict__ eraw,
                              int* __restrict__ flags, int* __restrict__ rowptr)
{
    __shared__ int s_insane, s_oddnz;
    if (threadIdx.x == 0) { s_insane = 0; s_oddnz = 0; }
    __syncthreads();
    int insane = 0;
    for (int i = threadIdx.x; i < 8192; i += 256) {
        const unsigned int bits = ((unsigned int)xraw[i]) << 16;
        const float v = __uint_as_float(bits);
        const float a = fabsf(v);
        const bool sane = (v == 0.0f) || (a >= 1e-30f && a <= 1e4f);
        if (!sane) insane++;
    }
    int oddnz = 0;
    for (int i = threadIdx.x; i < 512; i += 256) {
        if (eraw[2 * i + 1] != 0u) oddnz++;
    }
    atomicAdd(&s_insane, insane);
    atomicAdd(&s_oddnz, oddnz);
    __syncthreads();
    if (threadIdx.x == 0) {
        flags[0] = (s_insane < 256) ? 1 : 0;
        flags[1] = (s_oddnz == 0) ? 1 : 0;
        rowptr[NN] = ETOT;   // sentinel: rowptr holds immutable starts + end
    }
}

// ---------------- canonicalize weights to fp32 + build w1t (merged) ----------------
__global__ void conv_all_kernel(const void* W1, const void* as1, const void* ad1, const void* b1,
                                const void* W2, const void* as2, const void* ad2, const void* b2,
                                float* __restrict__ wc, unsigned short* __restrict__ w1t,
                                const int* __restrict__ flags)
{
    const int i = blockIdx.x * blockDim.x + threadIdx.x;
    const int isbf = flags[0];
    if (i < WTOT) {
        const void* src; int off;
        if (i < OAS1)      { src = W1;  off = i - OW1; }
        else if (i < OAD1) { src = as1; off = i - OAS1; }
        else if (i < OB1)  { src = ad1; off = i - OAD1; }
        else if (i < OW2)  { src = b1;  off = i - OB1; }
        else if (i < OAS2) { src = W2;  off = i - OW2; }
        else if (i < OAD2) { src = as2; off = i - OAS2; }
        else if (i < OB2)  { src = ad2; off = i - OAD2; }
        else               { src = b2;  off = i - OB2; }
        float v;
        if (isbf) v = b2f(((const bf16*)src)[off]);
        else      v = ((const float*)src)[off];
        wc[i] = v;
    }
    if (i < HC * KPAD) {
        const int col = i >> 9;
        const int k   = i & (KPAD - 1);
        float v = 0.f;
        if (k < FIN) {
            if (isbf) v = b2f(((const bf16*)W1)[k * HC + col]);
            else      v = ((const float*)W1)[k * HC + col];
        }
        w1t[i] = f2bu(v);
    }
}

// ---------------- CSR build: histogram of dst ----------------
__global__ void hist_kernel(const void* __restrict__ eidx, int* __restrict__ deg,
                            const int* __restrict__ flags)
{
    const int e = blockIdx.x * blockDim.x + threadIdx.x;
    if (e >= ETOT) return;
    int d;
    if (e < EE) d = eread(eidx, (long long)EE + e, flags[1]);
    else        d = e - EE;
    if ((unsigned)d < (unsigned)NN) atomicAdd(&deg[d], 1);
}

// ---------------- scan k1 ----------------
__global__ void scan_k1_kernel(const int* __restrict__ deg, int* __restrict__ bsum)
{
    __shared__ int lds[256];
    const int i = blockIdx.x * 256 + threadIdx.x;
    lds[threadIdx.x] = (i < NN) ? deg[i] : 0;
    __syncthreads();
    for (int s = 128; s > 0; s >>= 1) {
        if (threadIdx.x < s) lds[threadIdx.x] += lds[threadIdx.x + s];
        __syncthreads();
    }
    if (threadIdx.x == 0) bsum[blockIdx.x] = lds[0];
}

// ---------------- scan k2 ----------------
__global__ void scan_k2_kernel(int* __restrict__ bsum)
{
    __shared__ int a[256], b[256], orig[256];
    const int t = threadIdx.x;
    a[t] = bsum[t]; orig[t] = a[t];
    __syncthreads();
    int* cur = a; int* nxt = b;
    for (int off = 1; off < 256; off <<= 1) {
        nxt[t] = cur[t] + ((t >= off) ? cur[t - off] : 0);
        __syncthreads();
        int* tmp = cur; cur = nxt; nxt = tmp;
    }
    bsum[t] = cur[t] - orig[t];
}

// ---------------- scan k3: rowptr[i] = exclusive start of node i ----------------
__global__ void scan_k3_kernel(const int* __restrict__ deg, const int* __restrict__ bsum,
                               int* __restrict__ rowptr)
{
    __shared__ int a[256], b[256], own[256];
    const int t = threadIdx.x;
    const int i = blockIdx.x * 256 + t;
    const int v = (i < NN) ? deg[i] : 0;
    a[t] = v; own[t] = v;
    __syncthreads();
    int* cur = a; int* nxt = b;
    for (int off = 1; off < 256; off <<= 1) {
        nxt[t] = cur[t] + ((t >= off) ? cur[t - off] : 0);
        __syncthreads();
        int* tmp = cur; cur = nxt; nxt = tmp;
    }
    if (i < NN) rowptr[i] = bsum[blockIdx.x] + cur[t] - own[t];
}

// ---------------- CSR scatter: pos = rowptr[d] + atomic cursor ----------------
__global__ void scatter_kernel(const void* __restrict__ eidx, const int* __restrict__ rowptr,
                               int* __restrict__ cur, int* __restrict__ esrc_sorted,
                               const int* __restrict__ flags)
{
    const int e = blockIdx.x * blockDim.x + threadIdx.x;
    if (e >= ETOT) return;
    int s, d;
    if (e < EE) {
        s = eread(eidx, e, flags[1]);
        d = eread(eidx, (long long)EE + e, flags[1]);
    } else s = d = e - EE;
    if ((unsigned)s >= (unsigned)NN || (unsigned)d >= (unsigned)NN) return;
    const int pos = rowptr[d] + atomicAdd(&cur[d], 1);
    if ((unsigned)pos < (unsigned)ETOT) esrc_sorted[pos] = s;
}

// ---------------- GEMM1 v4: m97-style — gload B dbuf + reg-direct A ----------------
// 8 waves: 4 row-tiles (16 rows each) x 2 col-halves (64 cols). BK=64, 8 K-steps,
// ONE barrier per step. B tile gload'ed with XOR-swizzled source (T2/rule 21);
// A-fragments loaded straight from row-major x into registers (frag layout ==
// memory layout), one step ahead.
__global__ __launch_bounds__(512, 6) void gemm1_mfma_kernel(
    const void* __restrict__ x, const unsigned short* __restrict__ w1t,
    bf16* __restrict__ h1, const float* __restrict__ wc,
    float* __restrict__ a_src1, float* __restrict__ a_dst1,
    const int* __restrict__ flags)
{
    __shared__ __align__(16) unsigned char smem[34848];  // B dbuf 2x16KB; epi 64x132 f32
    __shared__ float attw[256];                          // as1[128] | ad1[128]

    unsigned short* const Bb0 = (unsigned short*)smem;
    unsigned short* const Bb1 = (unsigned short*)(smem + 16384);
    float (*Esl)[132] = (float (*)[132])smem;

    const int t    = threadIdx.x;      // 0..511
    const int wv   = t >> 6;
    const int lane = t & 63;
    const int m15  = lane & 15;
    const int quad = lane >> 4;
    const int r0   = blockIdx.x * BM;
    const int isbf = flags[0];
    const float* xf = (const float*)x;
    const unsigned short* xb = (const unsigned short*)x;

    if (t < 256) attw[t] = wc[OAS1 + t];   // OAD1 = OAS1+128: contiguous

    const int wr  = (wv >> 1) * 16;    // row-tile base within block
    const int wcb = (wv & 1) * 64;     // col-half base

    // A row for this lane's fragment (clamped: rows >= NN compute garbage that
    // is never stored; clamp keeps reads in-bounds)
    const int arow = min(r0 + wr + m15, NN - 1);

    // B gload source geometry: wave wv issues calls c in {2wv, 2wv+1};
    // call c covers cols c*8..c*8+7, 128B of k per col, source XOR-pre-swizzled.
    const int cA = 2 * wv, cB = 2 * wv + 1;
    const int colA = cA * 8 + (lane >> 3);
    const int colB = cB * 8 + (lane >> 3);
    const int xoA  = ((lane & 7) ^ (colA & 7)) * 8;
    const int xoB  = ((lane & 7) ^ (colB & 7)) * 8;
    const unsigned short* gBA = w1t + (size_t)colA * KPAD + xoA;
    const unsigned short* gBB = w1t + (size_t)colB * KPAD + xoB;

    f32x4 acc[4];
#pragma unroll
    for (int j = 0; j < 4; ++j) acc[j] = (f32x4){0.f, 0.f, 0.f, 0.f};

    // A fragment: 8 contiguous bf16 at (arow, kt*64 + sub*32 + quad*8).
    auto aload = [&](int kt, int sub) -> short8 {
        const int k = kt * BKK + sub * 32 + quad * 8;
        uint4 r = make_uint4(0u, 0u, 0u, 0u);
        if (isbf) {
            const unsigned short* p = xb + (size_t)arow * FIN + k;
            if (k + 8 <= FIN) {
                const uint2 lo = *(const uint2*)p;
                const uint2 hi = *(const uint2*)(p + 4);
                r.x = lo.x; r.y = lo.y; r.z = hi.x; r.w = hi.y;
            } else if (k + 4 <= FIN) {
                const uint2 lo = *(const uint2*)p;
                r.x = lo.x; r.y = lo.y;
            }
        } else {
            const float* p = xf + (size_t)arow * FIN + k;
            if (k + 8 <= FIN) {
                const float4 v0 = *(const float4*)p;
                const float4 v1 = *(const float4*)(p + 4);
                r.x = pk2(v0.x, v0.y); r.y = pk2(v0.z, v0.w);
                r.z = pk2(v1.x, v1.y); r.w = pk2(v1.z, v1.w);
            } else if (k + 4 <= FIN) {
                const float4 v0 = *(const float4*)p;
                r.x = pk2(v0.x, v0.y); r.y = pk2(v0.z, v0.w);
            }
        }
        return *(short8*)&r;
    };

    auto gloadB = [&](int kt, unsigned short* lbase) {
        const int k0 = kt * BKK;
        gload16(gBA + k0, lbase + (size_t)cA * 512);
        gload16(gBB + k0, lbase + (size_t)cB * 512);
    };

    auto compute = [&](const unsigned short* B, const short8 a0, const short8 a1) {
#pragma unroll
        for (int ct = 0; ct < 4; ++ct) {
            const int col  = wcb + ct * 16 + m15;
            const int base = col * 64;   // shorts
            const int sw   = (col & 7) << 4;
            const short8 b0 = *(const short8*)(B + base + (((0 * 64 + quad * 16) ^ sw) >> 1));
            acc[ct] = __builtin_amdgcn_mfma_f32_16x16x32_bf16(a0, b0, acc[ct], 0, 0, 0);
            const short8 b1 = *(const short8*)(B + base + (((1 * 64 + quad * 16) ^ sw) >> 1));
            acc[ct] = __builtin_amdgcn_mfma_f32_16x16x32_bf16(a1, b1, acc[ct], 0, 0, 0);
        }
    };

    // prologue
    gloadB(0, Bb0);
    short8 a0 = aload(0, 0);
    short8 a1 = aload(0, 1);
    __syncthreads();

#pragma unroll
    for (int kt = 0; kt < NKT; ++kt) {
        short8 n0 = a0, n1 = a1;
        if (kt < NKT - 1) {
            gloadB(kt + 1, ((kt + 1) & 1) ? Bb1 : Bb0);   // next-step B -> other buffer
            n0 = aload(kt + 1, 0);
            n1 = aload(kt + 1, 1);
        }
        compute((kt & 1) ? Bb1 : Bb0, a0, a1);
        __syncthreads();   // drains next-step gloads; protects buffer swap
        a0 = n0; a1 = n1;
    }

    // ---- epilogue: acc -> LDS f32 tile (aliases B buffers; post-barrier) ----
#pragma unroll
    for (int ct = 0; ct < 4; ++ct)
#pragma unroll
        for (int reg = 0; reg < 4; ++reg)
            Esl[wr + quad * 4 + reg][wcb + ct * 16 + m15] = acc[ct][reg];
    __syncthreads();

    {
        // thread t -> row t>>3 (0..63), 16 cols starting at (t&7)*16.
        //那 16 cols are exactly head (t&7)'s channels: one LDS read feeds both
        // the h1 store and the att1 dot products.
        const int row = t >> 3;
        const int hh  = t & 7;
        const int c0  = hh * 16;
        const int gr  = r0 + row;
        if (gr < NN) {
            float ep[16];
#pragma unroll
            for (int u = 0; u < 16; ++u) ep[u] = Esl[row][c0 + u];
            uint4 w0, w1;
            w0.x = pk2(ep[0],  ep[1]);  w0.y = pk2(ep[2],  ep[3]);
            w0.z = pk2(ep[4],  ep[5]);  w0.w = pk2(ep[6],  ep[7]);
            w1.x = pk2(ep[8],  ep[9]);  w1.y = pk2(ep[10], ep[11]);
            w1.z = pk2(ep[12], ep[13]); w1.w = pk2(ep[14], ep[15]);
            *(uint4*)(h1 + (size_t)gr * HC + c0)     = w0;
            *(uint4*)(h1 + (size_t)gr * HC + c0 + 8) = w1;

            float s = 0.f, d = 0.f;
#pragma unroll
            for (int u = 0; u < 16; ++u) {
                s += ep[u] * attw[c0 + u];
                d += ep[u] * attw[128 + c0 + u];
            }
            a_src1[(size_t)gr * NH + hh] = s;
            a_dst1[(size_t)gr * NH + hh] = d;
        }
    }
}

// ---------------- layer-1 fused gather + fused GEMM2/bias/relu + fused att2 ----------------
__global__ __launch_bounds__(256) void gather1_kernel(
    const int* __restrict__ rowptr, const int* __restrict__ esrc_sorted,
    const float* __restrict__ a_src, const float* __restrict__ a_dst,
    const bf16* __restrict__ h1, const float* __restrict__ wc,
    float* __restrict__ h2, float* __restrict__ a_src2, float* __restrict__ a_dst2)
{
    __shared__ float W2s[HC * NC];
    __shared__ float B1s[HC];
    for (int i = threadIdx.x; i < HC * NC; i += 256) W2s[i] = wc[OW2 + i];
    if (threadIdx.x < HC) B1s[threadIdx.x] = wc[OB1 + threadIdx.x];
    __syncthreads();

    const int node = blockIdx.x * 4 + (threadIdx.x >> 6);
    if (node >= NN) return;
    const int lane = threadIdx.x & 63;
    const int h = lane >> 3;
    const float ad = a_dst[node * NH + h];
    const int start = rowptr[node];
    const int end   = rowptr[node + 1];
    float acc0 = 0.f, acc1 = 0.f, den = 0.f;
    int i = start;
    for (; i + 8 <= end; i += 8) {
        int   sv[8];
        float ev[8];
        unsigned wv[8];
#pragma unroll
        for (int j = 0; j < 8; ++j) sv[j] = esrc_sorted[i + j];
#pragma unroll
        for (int j = 0; j < 8; ++j) ev[j] = a_src[sv[j] * NH + h];
#pragma unroll
        for (int j = 0; j < 8; ++j) wv[j] = *(const unsigned*)(h1 + (size_t)sv[j] * HC + 2 * lane);
#pragma unroll
        for (int j = 0; j < 8; ++j) {
            const float n = elog(ev[j] + ad);
            acc0 += n * blo(wv[j]);
            acc1 += n * bhi(wv[j]);
            den  += n;
        }
    }
    for (; i < end; ++i) {
        const int s = esrc_sorted[i];
        const float num = elog(a_src[s * NH + h] + ad);
        const unsigned w = *(const unsigned*)(h1 + (size_t)s * HC + 2 * lane);
        acc0 += num * blo(w);
        acc1 += num * bhi(w);
        den  += num;
    }
    const float inv = 1.f / (den + 1e-16f);

    // fused GEMM2: this wave holds the whole out1 row (2 channels / lane).
    const int k0 = 2 * lane;
    const float r0v = fmaxf(acc0 * inv + B1s[k0],     0.f);
    const float r1v = fmaxf(acc1 * inv + B1s[k0 + 1], 0.f);
    float p[NC];
#pragma unroll
    for (int c = 0; c < NC; ++c)
        p[c] = r0v * W2s[k0 * NC + c] + r1v * W2s[(k0 + 1) * NC + c];
    // 64-lane butterfly reduce (7 channels)
#pragma unroll
    for (int m = 1; m < 64; m <<= 1) {
#pragma unroll
        for (int c = 0; c < NC; ++c) p[c] += __shfl_xor(p[c], m);
    }
    if (lane == 0) {
        float ps = 0.f, pd = 0.f;
        float* hp = h2 + (size_t)node * NC;
#pragma unroll
        for (int c = 0; c < NC; ++c) {
            hp[c] = p[c];
            ps += p[c] * wc[OAS2 + c];
            pd += p[c] * wc[OAD2 + c];
        }
        a_src2[node] = ps;
        a_dst2[node] = pd;
    }
}

// ---------------- layer-2 fused gather ----------------
__global__ void gather2_kernel(
    const int* __restrict__ rowptr, const int* __restrict__ esrc_sorted,
    const float* __restrict__ a_src, const float* __restrict__ a_dst,
    const float* __restrict__ h2, const float* __restrict__ wc,
    void* __restrict__ out, const int* __restrict__ flags)
{
    const int node = blockIdx.x * 32 + (threadIdx.x >> 3);
    if (node >= NN) return;
    const int c = threadIdx.x & 7;
    const float ad = a_dst[node];
    const int start = rowptr[node];
    const int end   = rowptr[node + 1];
    const int cc = (c < NC) ? c : 0;
    float acc = 0.f, den = 0.f;
    int i = start;
    for (; i + 4 <= end; i += 4) {
        const int s0 = esrc_sorted[i + 0];
        const int s1 = esrc_sorted[i + 1];
        const int s2 = esrc_sorted[i + 2];
        const int s3 = esrc_sorted[i + 3];
        const float e0 = a_src[s0];
        const float e1 = a_src[s1];
        const float e2 = a_src[s2];
        const float e3 = a_src[s3];
        const float v0 = h2[s0 * NC + cc];
        const float v1 = h2[s1 * NC + cc];
        const float v2 = h2[s2 * NC + cc];
        const float v3 = h2[s3 * NC + cc];
        const float n0 = elog(e0 + ad);
        const float n1 = elog(e1 + ad);
        const float n2 = elog(e2 + ad);
        const float n3 = elog(e3 + ad);
        acc += n0 * v0 + n1 * v1 + n2 * v2 + n3 * v3;
        den += n0 + n1 + n2 + n3;
    }
    for (; i < end; ++i) {
        const int s = esrc_sorted[i];
        const float num = elog(a_src[s] + ad);
        den += num;
        acc += num * h2[s * NC + cc];
    }
    if (c >= NC) return;
    const float v = acc / (den + 1e-16f) + wc[OB2 + c];
    if (flags[0]) ((bf16*)out)[node * NC + c] = __float2bfloat16(v);
    else          ((float*)out)[node * NC + c] = v;
}

extern "C" void kernel_launch(void* const* d_in, const int* in_sizes, int n_in,
                              void* d_out, int out_size, void* d_ws, size_t ws_size,
                              hipStream_t stream)
{
    const void* x        = d_in[0];
    const void* eidx     = d_in[1];
    const void* W1       = d_in[2];
    const void* att_src1 = d_in[3];
    const void* att_dst1 = d_in[4];
    const void* b1       = d_in[5];
    const void* W2       = d_in[6];
    const void* att_src2 = d_in[7];
    const void* att_dst2 = d_in[8];
    const void* b2       = d_in[9];

    float* ws = (float*)d_ws;
    size_t o = 0;
    int*   flags  = (int*)(ws + o);            o += 16;
    float* wc     = ws + o;                    o += 65312;
    unsigned short* w1t = (unsigned short*)(ws + o); o += (HC * KPAD) / 2;
    int*   deg    = (int*)(ws + o);            o += 50000;
    int*   cur    = (int*)(ws + o);            o += 50000;   // contiguous with deg for one memset
    int*   rowptr = (int*)(ws + o);            o += 50016;
    int*   bsum   = (int*)(ws + o);            o += 256;
    int*   esrt   = (int*)(ws + o);            o += 850000;
    bf16*  h1     = (bf16*)(ws + o);           o += (size_t)NN * HC / 2;
    float* a_src1 = ws + o;                    o += (size_t)NN * NH;
    float* a_dst1 = ws + o;                    o += (size_t)NN * NH;
    float* h2     = ws + o;                    o += (size_t)NN * NC;
    float* a_src2 = ws + o;                    o += NN;
    float* a_dst2 = ws + o;                    o += NN;

    detect_kernel<<<1, 256, 0, stream>>>((const unsigned short*)x, (const unsigned int*)eidx,
                                         flags, rowptr);
    conv_all_kernel<<<(HC * KPAD + 255) / 256, 256, 0, stream>>>(
        W1, att_src1, att_dst1, b1, W2, att_src2, att_dst2, b2, wc, w1t, flags);
    hipMemsetAsync(deg, 0, 2 * (size_t)NN * sizeof(int), stream);
    hist_kernel<<<(ETOT + 255) / 256, 256, 0, stream>>>(eidx, deg, flags);
    scan_k1_kernel<<<(NN + 255) / 256, 256, 0, stream>>>(deg, bsum);
    scan_k2_kernel<<<1, 256, 0, stream>>>(bsum);
    scan_k3_kernel<<<(NN + 255) / 256, 256, 0, stream>>>(deg, bsum, rowptr);
    scatter_kernel<<<(ETOT + 255) / 256, 256, 0, stream>>>(eidx, rowptr, cur, esrt, flags);

    gemm1_mfma_kernel<<<(NN + BM - 1) / BM, 512, 0, stream>>>(x, w1t, h1, wc,
                                                              a_src1, a_dst1, flags);
    gather1_kernel<<<(NN + 3) / 4, 256, 0, stream>>>(rowptr, esrt, a_src1, a_dst1, h1, wc,
                                                     h2, a_src2, a_dst2);
    gather2_kernel<<<(NN + 31) / 32, 256, 0, stream>>>(rowptr, esrt, a_src2, a_dst2, h2, wc,
                                                       d_out, flags);
}